// Round 14
// baseline (292.374 us; speedup 1.0000x reference)
//
#include <hip/hip_runtime.h>
#include <hip/hip_bf16.h>
#include <hip/hip_cooperative_groups.h>

namespace cg = cooperative_groups;

// B=2, D=512, N=2048, H=8, head=64.
// Primary: single cooperative kernel (4 phases, job-stride loops, adaptive grid).
// Fallback: the R11 4-kernel pipeline if cooperative launch is rejected.

using bf16x8 = __attribute__((ext_vector_type(8))) __bf16;
using f32x4  = __attribute__((ext_vector_type(4))) float;
using f32x16 = __attribute__((ext_vector_type(16))) float;
using us8    = __attribute__((ext_vector_type(8))) unsigned short;
using u32x4  = __attribute__((ext_vector_type(4))) unsigned int;

__device__ __forceinline__ unsigned short f2b(float f) {
  unsigned int u = __builtin_bit_cast(unsigned int, f);
  u += 0x7fffu + ((u >> 16) & 1u);
  return (unsigned short)(u >> 16);
}
__device__ __forceinline__ unsigned int cvtpk(float lo, float hi) {
  unsigned int w;
  asm("v_cvt_pk_bf16_f32 %0, %1, %2" : "=v"(w) : "v"(lo), "v"(hi));
  return w;
}
__device__ __forceinline__ void gl_lds16(const void* g, void* l) {
  __builtin_amdgcn_global_load_lds((const __attribute__((address_space(1))) void*)g,
                                   (__attribute__((address_space(3))) void*)l, 16, 0, 0);
}

//=====================================================================
// Fused cooperative kernel
//=====================================================================
__global__ __launch_bounds__(256, 2) void k_fused(
    const float* __restrict__ fq, const float* __restrict__ fk, const int* __restrict__ msk,
    const float* __restrict__ Wq, const float* __restrict__ bq,
    const float* __restrict__ Wk, const float* __restrict__ bk,
    const float* __restrict__ Wf, const float* __restrict__ bfv,
    const float* __restrict__ Wm, const float* __restrict__ bm,
    const float* __restrict__ lng, const float* __restrict__ lnb,
    float* __restrict__ out,
    unsigned short* __restrict__ xqt, unsigned short* __restrict__ xkt,
    unsigned short* __restrict__ wqb, unsigned short* __restrict__ wkb,
    unsigned short* __restrict__ wfb, unsigned short* __restrict__ wmb,
    unsigned short* __restrict__ Qb, unsigned short* __restrict__ Kb,
    unsigned short* __restrict__ VTb, unsigned short* __restrict__ OTb,
    unsigned int* __restrict__ mbits)
{
  __shared__ __attribute__((aligned(16))) char lds_all[70656];
  const int bid = blockIdx.x;
  const int nb = gridDim.x;
  const int t = threadIdx.x;
  const int w = t >> 6, l = t & 63;
  cg::grid_group grid = cg::this_grid();

  //======== P0: feats transpose + weight permute + mask bitmap ========
  {
    float (*tile)[65] = (float (*)[65])lds_all;
    for (int id = bid; id < 1024; id += nb) {
      __syncthreads();
      const int which = id >> 9;
      const int b = (id >> 8) & 1;
      const int i0 = ((id >> 5) & 7) * 64;
      const int n0 = (id & 31) * 64;
      const float* __restrict__ src = which ? fk : fq;
      unsigned short* __restrict__ dst = which ? xkt : xqt;
      const int cl = t & 63, rw = t >> 6;
      #pragma unroll
      for (int rr = 0; rr < 16; ++rr) {
        int il = rr * 4 + rw;
        tile[il][cl] = src[((size_t)b * 512 + i0 + il) * 2048 + n0 + cl];
      }
      __syncthreads();
      const int ci = (t & 31) * 2, rhalf = t >> 5;
      #pragma unroll
      for (int rr = 0; rr < 8; ++rr) {
        int nl = rr * 8 + rhalf;
        unsigned int v = (unsigned int)f2b(tile[ci][nl]) |
                         ((unsigned int)f2b(tile[ci + 1][nl]) << 16);
        *(unsigned int*)&dst[((size_t)b * 2048 + n0 + nl) * 512 + i0 + ci] = v;
      }
    }
    for (int r = bid; r < 2048; r += nb) {
      int mat = r >> 9, cp = r & 511;
      if (mat < 3) {
        const float* W = (mat == 0) ? Wq : (mat == 1) ? Wk : Wf;
        unsigned short* O = (mat == 0) ? wqb : (mat == 1) ? wkb : wfb;
        const int orig = (cp & 63) * 8 + (cp >> 6);   // d*8+h
        for (int j = t; j < 512; j += 256)
          O[cp * 512 + j] = f2b(W[orig * 512 + j]);
      } else {
        for (int j = t; j < 512; j += 256) {
          int h = j >> 6, d = j & 63;
          wmb[cp * 512 + j] = f2b(Wm[cp * 512 + d * 8 + h]);
        }
      }
    }
    if (bid == 0 && t < 128) {
      int bb = t >> 6, wd = t & 63;
      unsigned int v = 0;
      #pragma unroll
      for (int j = 0; j < 32; ++j)
        v |= (msk[bb * 2048 + wd * 32 + j] ? 1u : 0u) << j;
      mbits[t] = v;
    }
  }
  __threadfence();
  grid.sync();

  //======== P1: QKV projections (768 jobs of 128x64 tiles) ========
  {
    const int q = l >> 4, m16 = l & 15;
    const int wm = w >> 1, wn = w & 1;
    const float QSCALE = 0.18033688011112042f;   // log2(e)/8 folded into Q

    for (int job = bid; job < 768; job += nb) {
      const int orig = (job & 7) * 96 + (job >> 3);   // bijective (768 = 8*96)
      const int z = orig / 128;
      const int bid2 = orig % 128;
      const int b = z / 3, proj = z % 3;

      const unsigned short* A;
      const unsigned short* Bt;
      int mt, nt_;
      if (proj < 2) {
        mt = bid2 >> 3; nt_ = bid2 & 7;
        A  = (proj == 0 ? xqt : xkt) + (size_t)b * 2048 * 512 + (size_t)mt * 128 * 512;
        Bt = (proj == 0 ? wqb : wkb) + (size_t)nt_ * 64 * 512;
      } else {
        mt = bid2 & 3; nt_ = bid2 >> 2;
        A  = wfb + (size_t)mt * 128 * 512;
        Bt = xkt + (size_t)b * 2048 * 512 + (size_t)nt_ * 64 * 512;
      }

      f32x4 acc[4][2];
      const f32x4 fz = {0.f, 0.f, 0.f, 0.f};
      #pragma unroll
      for (int mf = 0; mf < 4; ++mf)
        #pragma unroll
        for (int nf = 0; nf < 2; ++nf) acc[mf][nf] = fz;

      __syncthreads();   // LDS handoff

#define PROJ_STAGE(BUF, KS)                                                        \
  {                                                                                \
    _Pragma("unroll")                                                              \
    for (int c = 0; c < 4; ++c) {                                                  \
      int slot = c * 256 + t;                                                      \
      int row = slot >> 3, j = slot & 7;                                           \
      gl_lds16(A + (size_t)row * 512 + (KS) * 64 + ((j ^ (row & 7)) * 8),          \
               lds_all + (BUF) * 16384 + (c * 256 + w * 64) * 16);                 \
    }                                                                              \
    _Pragma("unroll")                                                              \
    for (int c = 0; c < 2; ++c) {                                                  \
      int slot = c * 256 + t;                                                      \
      int row = slot >> 3, j = slot & 7;                                           \
      gl_lds16(Bt + (size_t)row * 512 + (KS) * 64 + ((j ^ (row & 7)) * 8),         \
               lds_all + 32768 + (BUF) * 8192 + (c * 256 + w * 64) * 16);          \
    }                                                                              \
  }

      PROJ_STAGE(0, 0)
      asm volatile("s_waitcnt vmcnt(0)" ::: "memory");
      __syncthreads();

      for (int ks = 0; ks < 8; ++ks) {
        const int cur = ks & 1;
        if (ks < 7) PROJ_STAGE(cur ^ 1, ks + 1)
        #pragma unroll
        for (int kk = 0; kk < 2; ++kk) {
          bf16x8 av[4], bv[2];
          #pragma unroll
          for (int mf = 0; mf < 4; ++mf) {
            int row = wm * 64 + mf * 16 + m16;
            av[mf] = *(const bf16x8*)(lds_all + cur * 16384 + row * 128 +
                                      (((kk * 4 + q) ^ (row & 7)) * 16));
          }
          #pragma unroll
          for (int nf = 0; nf < 2; ++nf) {
            int row = wn * 32 + nf * 16 + m16;
            bv[nf] = *(const bf16x8*)(lds_all + 32768 + cur * 8192 + row * 128 +
                                      (((kk * 4 + q) ^ (row & 7)) * 16));
          }
          #pragma unroll
          for (int mf = 0; mf < 4; ++mf)
            #pragma unroll
            for (int nf = 0; nf < 2; ++nf)
              acc[mf][nf] = __builtin_amdgcn_mfma_f32_16x16x32_bf16(av[mf], bv[nf], acc[mf][nf], 0, 0, 0);
        }
        if (ks < 7) {
          asm volatile("s_waitcnt vmcnt(0)" ::: "memory");
          __syncthreads();
        }
      }
#undef PROJ_STAGE

      if (proj < 2) {
        const float* bias = (proj == 0) ? bq : bk;
        unsigned short* dst = (proj == 0) ? Qb : Kb;
        #pragma unroll
        for (int mf = 0; mf < 4; ++mf)
          #pragma unroll
          for (int nf = 0; nf < 2; ++nf)
            #pragma unroll
            for (int r = 0; r < 4; ++r) {
              int n  = mt * 128 + wm * 64 + mf * 16 + q * 4 + r;
              int cp = nt_ * 64 + wn * 32 + nf * 16 + m16;
              int h = cp >> 6, d = cp & 63;
              float v = acc[mf][nf][r] + bias[d * 8 + h];
              if (proj == 0) v *= QSCALE;
              dst[((size_t)(b * 8 + h) * 2048 + n) * 64 + d] = f2b(v);
            }
      } else {
        #pragma unroll
        for (int mf = 0; mf < 4; ++mf)
          #pragma unroll
          for (int nf = 0; nf < 2; ++nf)
            #pragma unroll
            for (int r = 0; r < 4; ++r) {
              int cp = mt * 128 + wm * 64 + mf * 16 + q * 4 + r;
              int n  = nt_ * 64 + wn * 32 + nf * 16 + m16;
              int h = cp >> 6, d = cp & 63;
              float v = acc[mf][nf][r] + bfv[d * 8 + h];
              VTb[((size_t)(b * 8 + h) * 64 + d) * 2048 + n] = f2b(v);
            }
      }
    }
  }
  __threadfence();
  grid.sync();

  //======== P2: flash attention (512 jobs; R11 body) ========
  for (int job = bid; job < 512; job += nb) {
    __syncthreads();   // LDS handoff
    const int orig = ((job & 7) << 6) | (job >> 3);   // bijective (512 = 8*64)
    const int bh = orig >> 5, b = bh >> 3, h = bh & 7;
    const int nt = orig & 31;
    const int q31 = l & 31, hi = l >> 5;

    char* kbuf = lds_all + w * 8192;
    char* vbuf = lds_all + 32768 + w * 8192;

    const unsigned short* Kp = Kb + (size_t)bh * (2048 * 64);
    const unsigned short* Vp = VTb + (size_t)bh * (64 * 2048);
    const unsigned int* mrow = mbits + b * 64;

    bf16x8 qfr[2][4];
    {
      const unsigned short* Qp = Qb + ((size_t)bh * 2048 + nt * 64) * 64;
      #pragma unroll
      for (int qf = 0; qf < 2; ++qf)
        #pragma unroll
        for (int tq = 0; tq < 4; ++tq)
          qfr[qf][tq] = *(const bf16x8*)&Qp[(qf * 32 + q31) * 64 + tq * 16 + hi * 8];
    }

    f32x16 z16;
    #pragma unroll
    for (int r = 0; r < 16; ++r) z16[r] = 0.f;
    f32x16 oacc[2][2];
    #pragma unroll
    for (int i = 0; i < 2; ++i)
      #pragma unroll
      for (int j2 = 0; j2 < 2; ++j2) oacc[i][j2] = z16;
    float lpart[2] = {0.f, 0.f};

    const int kr3 = l >> 3, ks3 = l & 7;
    const int vr4 = l >> 2, vs2 = l & 3;

    {
      int kv0 = w * 32;
      #pragma unroll
      for (int j = 0; j < 4; ++j)
        gl_lds16(Kp + (size_t)(kv0 + j * 8 + kr3) * 64 + (ks3 ^ kr3) * 8, kbuf + j * 1024);
      #pragma unroll
      for (int j = 0; j < 4; ++j) {
        int d = j * 16 + vr4;
        gl_lds16(Vp + (size_t)d * 2048 + kv0 + (vs2 ^ (d & 3)) * 8, vbuf + j * 1024);
      }
    }

    #pragma unroll 2
    for (int i = 0; i < 16; ++i) {
      const int bufi = i & 1;
      const unsigned int mword = mrow[w + 4 * i];
      const unsigned int mw2 = mword >> (hi * 4);

      if (i < 15) {
        const int kvn = (w + 4 * (i + 1)) * 32;
        char* kb2 = kbuf + (bufi ^ 1) * 4096;
        char* vb2 = vbuf + (bufi ^ 1) * 4096;
        #pragma unroll
        for (int j = 0; j < 4; ++j)
          gl_lds16(Kp + (size_t)(kvn + j * 8 + kr3) * 64 + (ks3 ^ kr3) * 8, kb2 + j * 1024);
        #pragma unroll
        for (int j = 0; j < 4; ++j) {
          int d = j * 16 + vr4;
          gl_lds16(Vp + (size_t)d * 2048 + kvn + (vs2 ^ (d & 3)) * 8, vb2 + j * 1024);
        }
        asm volatile("s_waitcnt vmcnt(8)" ::: "memory");
      } else {
        asm volatile("s_waitcnt vmcnt(0)" ::: "memory");
      }
      __builtin_amdgcn_sched_barrier(0);

      const char* kb = kbuf + bufi * 4096;
      const char* vb = vbuf + bufi * 4096;

      bf16x8 ak[4];
      #pragma unroll
      for (int tq = 0; tq < 4; ++tq)
        ak[tq] = *(const bf16x8*)(kb + q31 * 128 + ((((tq << 1) | hi) ^ (q31 & 7)) * 16));

      f32x16 sacc[2];
      __builtin_amdgcn_s_setprio(1);
      sacc[0] = __builtin_amdgcn_mfma_f32_32x32x16_bf16(ak[0], qfr[0][0], z16, 0, 0, 0);
      sacc[1] = __builtin_amdgcn_mfma_f32_32x32x16_bf16(ak[0], qfr[1][0], z16, 0, 0, 0);
      #pragma unroll
      for (int tq = 1; tq < 4; ++tq) {
        sacc[0] = __builtin_amdgcn_mfma_f32_32x32x16_bf16(ak[tq], qfr[0][tq], sacc[0], 0, 0, 0);
        sacc[1] = __builtin_amdgcn_mfma_f32_32x32x16_bf16(ak[tq], qfr[1][tq], sacc[1], 0, 0, 0);
      }
      __builtin_amdgcn_s_setprio(0);

      bf16x8 av[2][2];
      #pragma unroll
      for (int df = 0; df < 2; ++df)
        #pragma unroll
        for (int tt = 0; tt < 2; ++tt)
          av[df][tt] = *(const bf16x8*)(vb + (df * 32 + q31) * 64 + ((((tt << 1) | hi) ^ (q31 & 3)) * 16));

      #pragma unroll
      for (int qf = 0; qf < 2; ++qf) {
        float e[16];
        #pragma unroll
        for (int g = 0; g < 4; ++g)
          #pragma unroll
          for (int r2 = 0; r2 < 4; ++r2) {
            float ev = __builtin_amdgcn_exp2f(sacc[qf][g * 4 + r2]);
            e[g * 4 + r2] = ((mw2 >> (r2 + 8 * g)) & 1u) ? ev : 0.f;
          }
        float s0 = 0.f;
        #pragma unroll
        for (int r = 0; r < 16; ++r) s0 += e[r];
        lpart[qf] += s0;

        unsigned int W[8];
        #pragma unroll
        for (int j = 0; j < 8; ++j) W[j] = cvtpk(e[2*j], e[2*j+1]);
        asm("v_permlane32_swap_b32 %0, %1" : "+v"(W[0]), "+v"(W[2]));
        asm("v_permlane32_swap_b32 %0, %1" : "+v"(W[1]), "+v"(W[3]));
        asm("v_permlane32_swap_b32 %0, %1" : "+v"(W[4]), "+v"(W[6]));
        asm("v_permlane32_swap_b32 %0, %1" : "+v"(W[5]), "+v"(W[7]));
        u32x4 lo4 = {W[0], W[1], W[2], W[3]};
        u32x4 hi4 = {W[4], W[5], W[6], W[7]};
        bf16x8 pb0 = __builtin_bit_cast(bf16x8, lo4);
        bf16x8 pb1 = __builtin_bit_cast(bf16x8, hi4);

        __builtin_amdgcn_s_setprio(1);
        oacc[0][qf] = __builtin_amdgcn_mfma_f32_32x32x16_bf16(av[0][0], pb0, oacc[0][qf], 0, 0, 0);
        oacc[0][qf] = __builtin_amdgcn_mfma_f32_32x32x16_bf16(av[0][1], pb1, oacc[0][qf], 0, 0, 0);
        oacc[1][qf] = __builtin_amdgcn_mfma_f32_32x32x16_bf16(av[1][0], pb0, oacc[1][qf], 0, 0, 0);
        oacc[1][qf] = __builtin_amdgcn_mfma_f32_32x32x16_bf16(av[1][1], pb1, oacc[1][qf], 0, 0, 0);
        __builtin_amdgcn_s_setprio(0);
      }
    }

    float* pc = (float*)lds_all;
    float* ls = (float*)(lds_all + 69632);
    __syncthreads();
    #pragma unroll
    for (int qf = 0; qf < 2; ++qf) {
      float lfull = lpart[qf] + __shfl_xor(lpart[qf], 32);
      int qq = qf * 32 + q31;
      if (hi == 0) ls[w * 64 + qq] = lfull;
      #pragma unroll
      for (int df = 0; df < 2; ++df)
        #pragma unroll
        for (int g = 0; g < 4; ++g) {
          f32x4 v4 = {oacc[df][qf][g*4+0], oacc[df][qf][g*4+1],
                      oacc[df][qf][g*4+2], oacc[df][qf][g*4+3]};
          *(f32x4*)&pc[w * 4352 + qq * 68 + df * 32 + g * 8 + hi * 4] = v4;
        }
    }
    __syncthreads();
    {
      const int q = t >> 2, ds = (t & 3) * 16;
      float lsumv = ls[q] + ls[64 + q] + ls[128 + q] + ls[192 + q];
      f32x4 o4[4];
      #pragma unroll
      for (int j = 0; j < 4; ++j) o4[j] = *(const f32x4*)&pc[q * 68 + ds + j * 4];
      #pragma unroll
      for (int ww = 1; ww < 4; ++ww)
        #pragma unroll
        for (int j = 0; j < 4; ++j) {
          f32x4 p4 = *(const f32x4*)&pc[ww * 4352 + q * 68 + ds + j * 4];
          o4[j] += p4;
        }
      float rinv = __builtin_amdgcn_rcpf(lsumv);
      unsigned int pk[8];
      #pragma unroll
      for (int j = 0; j < 4; ++j) {
        pk[2*j]   = cvtpk(o4[j][0] * rinv, o4[j][1] * rinv);
        pk[2*j+1] = cvtpk(o4[j][2] * rinv, o4[j][3] * rinv);
      }
      unsigned short* dst = &OTb[((size_t)b * 2048 + nt * 64 + q) * 512 + h * 64 + ds];
      u32x4 s0 = {pk[0], pk[1], pk[2], pk[3]};
      u32x4 s1 = {pk[4], pk[5], pk[6], pk[7]};
      *(u32x4*)dst = s0;
      *(u32x4*)(dst + 8) = s1;
    }
  }
  __threadfence();
  grid.sync();

  //======== P3: final proj + residual + channel-LN (256 jobs of 16 rows, BK=32) ========
  for (int job = bid; job < 256; job += nb) {
    __syncthreads();
    float* ssum = (float*)(lds_all + 67584);
    float* ssq  = (float*)(lds_all + 67840);

    const int b = job >> 7;
    const int n0 = (job & 127) * 16;
    const int q = l >> 4, m16 = l & 15;

    f32x4 acc[8];
    const f32x4 fz = {0.f, 0.f, 0.f, 0.f};
    #pragma unroll
    for (int nf = 0; nf < 8; ++nf) acc[nf] = fz;

    const unsigned short* Abase = OTb + ((size_t)b * 2048 + n0) * 512;
    const unsigned short* Bbase = wmb;

#define OUT_STAGE(BUF, KS)                                                         \
  {                                                                                \
    if (w == 0) {                                                                  \
      int row = l >> 2, j = l & 3;                                                 \
      gl_lds16(Abase + (size_t)row * 512 + (KS) * 32 + ((j ^ (row & 3)) * 8),      \
               lds_all + 65536 + (BUF) * 1024 + l * 16);                           \
    }                                                                              \
    _Pragma("unroll")                                                              \
    for (int c = 0; c < 8; ++c) {                                                  \
      int slot = c * 256 + t;                                                      \
      int row = slot >> 2, j = slot & 3;                                           \
      gl_lds16(Bbase + (size_t)row * 512 + (KS) * 32 + ((j ^ (row & 3)) * 8),      \
               lds_all + (BUF) * 32768 + (c * 256 + w * 64) * 16);                 \
    }                                                                              \
  }

    OUT_STAGE(0, 0)
    asm volatile("s_waitcnt vmcnt(0)" ::: "memory");
    __syncthreads();

    for (int ks = 0; ks < 16; ++ks) {
      const int cur = ks & 1;
      if (ks < 15) OUT_STAGE(cur ^ 1, ks + 1)
      {
        bf16x8 avv = *(const bf16x8*)(lds_all + 65536 + cur * 1024 + m16 * 64 +
                                      ((q ^ (m16 & 3)) * 16));
        #pragma unroll
        for (int nf = 0; nf < 8; ++nf) {
          int row = w * 128 + nf * 16 + m16;
          bf16x8 bv = *(const bf16x8*)(lds_all + cur * 32768 + row * 64 +
                                       ((q ^ (row & 3)) * 16));
          acc[nf] = __builtin_amdgcn_mfma_f32_16x16x32_bf16(avv, bv, acc[nf], 0, 0, 0);
        }
      }
      if (ks < 15) {
        asm volatile("s_waitcnt vmcnt(0)" ::: "memory");
        __syncthreads();
      }
    }
#undef OUT_STAGE

    float gv[8], bev[8], bmv[8];
    #pragma unroll
    for (int nf = 0; nf < 8; ++nf) {
      int c = w * 128 + nf * 16 + m16;
      gv[nf] = lng[c]; bev[nf] = lnb[c]; bmv[nf] = bm[c];
    }
    #pragma unroll
    for (int nf = 0; nf < 8; ++nf) {
      int c = w * 128 + nf * 16 + m16;
      f32x4 res = *(const f32x4*)&fq[((size_t)b * 512 + c) * 2048 + n0 + q * 4];
      #pragma unroll
      for (int r = 0; r < 4; ++r)
        acc[nf][r] += bmv[nf] + res[r];
    }
    #pragma unroll
    for (int r = 0; r < 4; ++r) {
      float ps = 0.f, pss = 0.f;
      #pragma unroll
      for (int nf = 0; nf < 8; ++nf) {
        float v = acc[nf][r];
        ps += v; pss += v * v;
      }
      ps += __shfl_xor(ps, 1); pss += __shfl_xor(pss, 1);
      ps += __shfl_xor(ps, 2); pss += __shfl_xor(pss, 2);
      ps += __shfl_xor(ps, 4); pss += __shfl_xor(pss, 4);
      ps += __shfl_xor(ps, 8); pss += __shfl_xor(pss, 8);
      if (m16 == 0) {
        ssum[w * 16 + q * 4 + r] = ps;
        ssq[w * 16 + q * 4 + r] = pss;
      }
    }
    __syncthreads();
    #pragma unroll
    for (int r = 0; r < 4; ++r) {
      int nl = q * 4 + r;
      float S  = ssum[nl] + ssum[16 + nl] + ssum[32 + nl] + ssum[48 + nl];
      float SS = ssq[nl] + ssq[16 + nl] + ssq[32 + nl] + ssq[48 + nl];
      float mu = S * (1.f / 512.f);
      float var = SS * (1.f / 512.f) - mu * mu;
      float rstd = rsqrtf(var + 1e-5f);
      #pragma unroll
      for (int nf = 0; nf < 8; ++nf)
        acc[nf][r] = (acc[nf][r] - mu) * rstd * gv[nf] + bev[nf];
    }
    #pragma unroll
    for (int nf = 0; nf < 8; ++nf) {
      int c = w * 128 + nf * 16 + m16;
      *(f32x4*)&out[((size_t)b * 512 + c) * 2048 + n0 + q * 4] = acc[nf];
    }
  }
}

//=====================================================================
// Fallback: R11 4-kernel pipeline (proven, 68.7 us)
//=====================================================================
__global__ __launch_bounds__(256) void k_pre(
    const float* __restrict__ fq, const float* __restrict__ fk,
    const float* __restrict__ Wq, const float* __restrict__ Wk,
    const float* __restrict__ Wf, const float* __restrict__ Wm,
    const int* __restrict__ mask,
    unsigned short* __restrict__ xqt, unsigned short* __restrict__ xkt,
    unsigned short* __restrict__ wqb, unsigned short* __restrict__ wkb,
    unsigned short* __restrict__ wfb, unsigned short* __restrict__ wmb,
    unsigned int* __restrict__ mbits)
{
  const int id = blockIdx.x;
  const int t = threadIdx.x;
  __shared__ float tile[64][65];

  if (id < 1024) {
    const int which = id >> 9;
    const int b = (id >> 8) & 1;
    const int i0 = ((id >> 5) & 7) * 64;
    const int n0 = (id & 31) * 64;
    const float* __restrict__ src = which ? fk : fq;
    unsigned short* __restrict__ dst = which ? xkt : xqt;
    const int cl = t & 63, rw = t >> 6;
    #pragma unroll
    for (int rr = 0; rr < 16; ++rr) {
      int il = rr * 4 + rw;
      tile[il][cl] = src[((size_t)b * 512 + i0 + il) * 2048 + n0 + cl];
    }
    __syncthreads();
    const int ci = (t & 31) * 2, rhalf = t >> 5;
    #pragma unroll
    for (int rr = 0; rr < 8; ++rr) {
      int nl = rr * 8 + rhalf;
      unsigned int v = (unsigned int)f2b(tile[ci][nl]) |
                       ((unsigned int)f2b(tile[ci + 1][nl]) << 16);
      *(unsigned int*)&dst[((size_t)b * 2048 + n0 + nl) * 512 + i0 + ci] = v;
    }
  } else if (id < 3072) {
    const int r = id - 1024;
    const int mat = r >> 9, cp = r & 511;
    if (mat < 3) {
      const float* W = (mat == 0) ? Wq : (mat == 1) ? Wk : Wf;
      unsigned short* O = (mat == 0) ? wqb : (mat == 1) ? wkb : wfb;
      const int orig = (cp & 63) * 8 + (cp >> 6);
      for (int j = t; j < 512; j += 256)
        O[cp * 512 + j] = f2b(W[orig * 512 + j]);
    } else {
      for (int j = t; j < 512; j += 256) {
        int h = j >> 6, d = j & 63;
        wmb[cp * 512 + j] = f2b(Wm[cp * 512 + d * 8 + h]);
      }
    }
  } else {
    if (t < 128) {
      int bb = t >> 6, wd = t & 63;
      unsigned int v = 0;
      #pragma unroll
      for (int j = 0; j < 32; ++j)
        v |= (mask[bb * 2048 + wd * 32 + j] ? 1u : 0u) << j;
      mbits[t] = v;
    }
  }
}

__global__ __launch_bounds__(256) void k_proj(
    const unsigned short* __restrict__ xqt, const unsigned short* __restrict__ xkt,
    const unsigned short* __restrict__ wqp, const unsigned short* __restrict__ wkp,
    const unsigned short* __restrict__ wfp,
    const float* __restrict__ bq, const float* __restrict__ bk, const float* __restrict__ bfv,
    unsigned short* __restrict__ Qb, unsigned short* __restrict__ Kb, unsigned short* __restrict__ VTb)
{
  const int lid = blockIdx.x;
  const int orig = (lid & 7) * 96 + (lid >> 3);
  const int z = orig / 128;
  const int bid = orig % 128;
  const int b = z / 3, proj = z % 3;
  const int t = threadIdx.x, w = t >> 6, l = t & 63, q = l >> 4, m16 = l & 15;
  const int wm = w >> 1, wn = w & 1;

  __shared__ __attribute__((aligned(16))) unsigned short As[2][8192];
  __shared__ __attribute__((aligned(16))) unsigned short Bs[2][4096];

  const unsigned short* A;
  const unsigned short* Bt;
  int mt, nt_;
  if (proj < 2) {
    mt = bid >> 3; nt_ = bid & 7;
    A  = (proj == 0 ? xqt : xkt) + (size_t)b * 2048 * 512 + (size_t)mt * 128 * 512;
    Bt = (proj == 0 ? wqp : wkp) + (size_t)nt_ * 64 * 512;
  } else {
    mt = bid & 3; nt_ = bid >> 2;
    A  = wfp + (size_t)mt * 128 * 512;
    Bt = xkt + (size_t)b * 2048 * 512 + (size_t)nt_ * 64 * 512;
  }

  f32x4 acc[4][2];
  const f32x4 fz = {0.f, 0.f, 0.f, 0.f};
  #pragma unroll
  for (int mf = 0; mf < 4; ++mf)
    #pragma unroll
    for (int nf = 0; nf < 2; ++nf) acc[mf][nf] = fz;

#define PROJ_STAGE(BUF, KS)                                                          \
  {                                                                                  \
    _Pragma("unroll")                                                                \
    for (int c = 0; c < 4; ++c) {                                                    \
      int slot = c * 256 + t;                                                        \
      int row = slot >> 3, j = slot & 7;                                             \
      gl_lds16(A + (size_t)row * 512 + (KS) * 64 + ((j ^ (row & 7)) * 8),            \
               (char*)As[BUF] + (c * 256 + w * 64) * 16);                            \
    }                                                                                \
    _Pragma("unroll")                                                                \
    for (int c = 0; c < 2; ++c) {                                                    \
      int slot = c * 256 + t;                                                        \
      int row = slot >> 3, j = slot & 7;                                             \
      gl_lds16(Bt + (size_t)row * 512 + (KS) * 64 + ((j ^ (row & 7)) * 8),           \
               (char*)Bs[BUF] + (c * 256 + w * 64) * 16);                            \
    }                                                                                \
  }

  PROJ_STAGE(0, 0)
  asm volatile("s_waitcnt vmcnt(0)" ::: "memory");
  __syncthreads();

  for (int ks = 0; ks < 8; ++ks) {
    const int cur = ks & 1;
    if (ks < 7) PROJ_STAGE(cur ^ 1, ks + 1)
    #pragma unroll
    for (int kk = 0; kk < 2; ++kk) {
      bf16x8 av[4], bv[2];
      #pragma unroll
      for (int mf = 0; mf < 4; ++mf) {
        int row = wm * 64 + mf * 16 + m16;
        av[mf] = *(const bf16x8*)&As[cur][row * 64 + (((kk * 4 + q) ^ (row & 7)) << 3)];
      }
      #pragma unroll
      for (int nf = 0; nf < 2; ++nf) {
        int row = wn * 32 + nf * 16 + m16;
        bv[nf] = *(const bf16x8*)&Bs[cur][row * 64 + (((kk * 4 + q) ^ (row & 7)) << 3)];
      }
      #pragma unroll
      for (int mf = 0; mf < 4; ++mf)
        #pragma unroll
        for (int nf = 0; nf < 2; ++nf)
          acc[mf][nf] = __builtin_amdgcn_mfma_f32_16x16x32_bf16(av[mf], bv[nf], acc[mf][nf], 0, 0, 0);
    }
    if (ks < 7) {
      asm volatile("s_waitcnt vmcnt(0)" ::: "memory");
      __syncthreads();
    }
  }
#undef PROJ_STAGE

  const float QSCALE = 0.18033688011112042f;

  if (proj < 2) {
    const float* bias = (proj == 0) ? bq : bk;
    unsigned short* dst = (proj == 0) ? Qb : Kb;
    #pragma unroll
    for (int mf = 0; mf < 4; ++mf)
      #pragma unroll
      for (int nf = 0; nf < 2; ++nf)
        #pragma unroll
        for (int r = 0; r < 4; ++r) {
          int n  = mt * 128 + wm * 64 + mf * 16 + q * 4 + r;
          int cp = nt_ * 64 + wn * 32 + nf * 16 + m16;
          int h = cp >> 6, d = cp & 63;
          float v = acc[mf][nf][r] + bias[d * 8 + h];
          if (proj == 0) v *= QSCALE;
          dst[((size_t)(b * 8 + h) * 2048 + n) * 64 + d] = f2b(v);
        }
  } else {
    #pragma unroll
    for (int mf = 0; mf < 4; ++mf)
      #pragma unroll
      for (int nf = 0; nf < 2; ++nf)
        #pragma unroll
        for (int r = 0; r < 4; ++r) {
          int cp = mt * 128 + wm * 64 + mf * 16 + q * 4 + r;
          int n  = nt_ * 64 + wn * 32 + nf * 16 + m16;
          int h = cp >> 6, d = cp & 63;
          float v = acc[mf][nf][r] + bfv[d * 8 + h];
          VTb[((size_t)(b * 8 + h) * 64 + d) * 2048 + n] = f2b(v);
        }
  }
}

__global__ __launch_bounds__(256, 2) void k_attn2(
    const unsigned short* __restrict__ Qb, const unsigned short* __restrict__ Kb,
    const unsigned short* __restrict__ VTb, const unsigned int* __restrict__ mbits,
    unsigned short* __restrict__ OT)
{
  const int lid = blockIdx.x;
  const int orig = ((lid & 7) << 6) | (lid >> 3);
  const int bh = orig >> 5, b = bh >> 3, h = bh & 7;
  const int nt = orig & 31;
  const int t = threadIdx.x, w = t >> 6, l = t & 63;
  const int q31 = l & 31, hi = l >> 5;

  __shared__ __attribute__((aligned(16))) char lds_all[70656];
  char* kbuf = lds_all + w * 8192;
  char* vbuf = lds_all + 32768 + w * 8192;

  const unsigned short* Kp = Kb + (size_t)bh * (2048 * 64);
  const unsigned short* Vp = VTb + (size_t)bh * (64 * 2048);
  const unsigned int* mrow = mbits + b * 64;

  bf16x8 qfr[2][4];
  {
    const unsigned short* Qp = Qb + ((size_t)bh * 2048 + nt * 64) * 64;
    #pragma unroll
    for (int qf = 0; qf < 2; ++qf)
      #pragma unroll
      for (int tq = 0; tq < 4; ++tq)
        qfr[qf][tq] = *(const bf16x8*)&Qp[(qf * 32 + q31) * 64 + tq * 16 + hi * 8];
  }

  f32x16 z16;
  #pragma unroll
  for (int r = 0; r < 16; ++r) z16[r] = 0.f;
  f32x16 oacc[2][2];
  #pragma unroll
  for (int i = 0; i < 2; ++i)
    #pragma unroll
    for (int j2 = 0; j2 < 2; ++j2) oacc[i][j2] = z16;
  float lpart[2] = {0.f, 0.f};

  const int kr3 = l >> 3, ks3 = l & 7;
  const int vr4 = l >> 2, vs2 = l & 3;

  {
    int kv0 = w * 32;
    #pragma unroll
    for (int j = 0; j < 4; ++j)
      gl_lds16(Kp + (size_t)(kv0 + j * 8 + kr3) * 64 + (ks3 ^ kr3) * 8, kbuf + j * 1024);
    #pragma unroll
    for (int j = 0; j < 4; ++j) {
      int d = j * 16 + vr4;
      gl_lds16(Vp + (size_t)d * 2048 + kv0 + (vs2 ^ (d & 3)) * 8, vbuf + j * 1024);
    }
  }

  #pragma unroll 2
  for (int i = 0; i < 16; ++i) {
    const int bufi = i & 1;
    const unsigned int mword = mrow[w + 4 * i];
    const unsigned int mw2 = mword >> (hi * 4);

    if (i < 15) {
      const int kvn = (w + 4 * (i + 1)) * 32;
      char* kb2 = kbuf + (bufi ^ 1) * 4096;
      char* vb2 = vbuf + (bufi ^ 1) * 4096;
      #pragma unroll
      for (int j = 0; j < 4; ++j)
        gl_lds16(Kp + (size_t)(kvn + j * 8 + kr3) * 64 + (ks3 ^ kr3) * 8, kb2 + j * 1024);
      #pragma unroll
      for (int j = 0; j < 4; ++j) {
        int d = j * 16 + vr4;
        gl_lds16(Vp + (size_t)d * 2048 + kvn + (vs2 ^ (d & 3)) * 8, vb2 + j * 1024);
      }
      asm volatile("s_waitcnt vmcnt(8)" ::: "memory");
    } else {
      asm volatile("s_waitcnt vmcnt(0)" ::: "memory");
    }
    __builtin_amdgcn_sched_barrier(0);

    const char* kb = kbuf + bufi * 4096;
    const char* vb = vbuf + bufi * 4096;

    bf16x8 ak[4];
    #pragma unroll
    for (int tq = 0; tq < 4; ++tq)
      ak[tq] = *(const bf16x8*)(kb + q31 * 128 + ((((tq << 1) | hi) ^ (q31 & 7)) * 16));

    f32x16 sacc[2];
    __builtin_amdgcn_s_setprio(1);
    sacc[0] = __builtin_amdgcn_mfma_f32_32x32x16_bf16(ak[0], qfr[0][0], z16, 0, 0, 0);
    sacc[1] = __builtin_amdgcn_mfma_f32_32x32x16_bf16(ak[0], qfr[1][0], z16, 0, 0, 0);
    #pragma unroll
    for (int tq = 1; tq < 4; ++tq) {
      sacc[0] = __builtin_amdgcn_mfma_f32_32x32x16_bf16(ak[tq], qfr[0][tq], sacc[0], 0, 0, 0);
      sacc[1] = __builtin_amdgcn_mfma_f32_32x32x16_bf16(ak[tq], qfr[1][tq], sacc[1], 0, 0, 0);
    }
    __builtin_amdgcn_s_setprio(0);

    bf16x8 av[2][2];
    #pragma unroll
    for (int df = 0; df < 2; ++df)
      #pragma unroll
      for (int tt = 0; tt < 2; ++tt)
        av[df][tt] = *(const bf16x8*)(vb + (df * 32 + q31) * 64 + ((((tt << 1) | hi) ^ (q31 & 3)) * 16));

    #pragma unroll
    for (int qf = 0; qf < 2; ++qf) {
      float e[16];
      #pragma unroll
      for (int g = 0; g < 4; ++g)
        #pragma unroll
        for (int r2 = 0; r2 < 4; ++r2) {
          float ev = __builtin_amdgcn_exp2f(sacc[qf][g * 4 + r2]);
          e[g * 4 + r2] = ((mw2 >> (r2 + 8 * g)) & 1u) ? ev : 0.f;
        }
      float s0 = 0.f;
      #pragma unroll
      for (int r = 0; r < 16; ++r) s0 += e[r];
      lpart[qf] += s0;

      unsigned int W[8];
      #pragma unroll
      for (int j = 0; j < 8; ++j) W[j] = cvtpk(e[2*j], e[2*j+1]);
      asm("v_permlane32_swap_b32 %0, %1" : "+v"(W[0]), "+v"(W[2]));
      asm("v_permlane32_swap_b32 %0, %1" : "+v"(W[1]), "+v"(W[3]));
      asm("v_permlane32_swap_b32 %0, %1" : "+v"(W[4]), "+v"(W[6]));
      asm("v_permlane32_swap_b32 %0, %1" : "+v"(W[5]), "+v"(W[7]));
      u32x4 lo4 = {W[0], W[1], W[2], W[3]};
      u32x4 hi4 = {W[4], W[5], W[6], W[7]};
      bf16x8 pb0 = __builtin_bit_cast(bf16x8, lo4);
      bf16x8 pb1 = __builtin_bit_cast(bf16x8, hi4);

      __builtin_amdgcn_s_setprio(1);
      oacc[0][qf] = __builtin_amdgcn_mfma_f32_32x32x16_bf16(av[0][0], pb0, oacc[0][qf], 0, 0, 0);
      oacc[0][qf] = __builtin_amdgcn_mfma_f32_32x32x16_bf16(av[0][1], pb1, oacc[0][qf], 0, 0, 0);
      oacc[1][qf] = __builtin_amdgcn_mfma_f32_32x32x16_bf16(av[1][0], pb0, oacc[1][qf], 0, 0, 0);
      oacc[1][qf] = __builtin_amdgcn_mfma_f32_32x32x16_bf16(av[1][1], pb1, oacc[1][qf], 0, 0, 0);
      __builtin_amdgcn_s_setprio(0);
    }
  }

  float* pc = (float*)lds_all;
  float* ls = (float*)(lds_all + 69632);
  __syncthreads();
  #pragma unroll
  for (int qf = 0; qf < 2; ++qf) {
    float lfull = lpart[qf] + __shfl_xor(lpart[qf], 32);
    int qq = qf * 32 + q31;
    if (hi == 0) ls[w * 64 + qq] = lfull;
    #pragma unroll
    for (int df = 0; df < 2; ++df)
      #pragma unroll
      for (int g = 0; g < 4; ++g) {
        f32x4 v4 = {oacc[df][qf][g*4+0], oacc[df][qf][g*4+1],
                    oacc[df][qf][g*4+2], oacc[df][qf][g*4+3]};
        *(f32x4*)&pc[w * 4352 + qq * 68 + df * 32 + g * 8 + hi * 4] = v4;
      }
  }
  __syncthreads();
  {
    const int q = t >> 2, ds = (t & 3) * 16;
    float lsumv = ls[q] + ls[64 + q] + ls[128 + q] + ls[192 + q];
    f32x4 o4[4];
    #pragma unroll
    for (int j = 0; j < 4; ++j) o4[j] = *(const f32x4*)&pc[q * 68 + ds + j * 4];
    #pragma unroll
    for (int ww = 1; ww < 4; ++ww)
      #pragma unroll
      for (int j = 0; j < 4; ++j) {
        f32x4 p4 = *(const f32x4*)&pc[ww * 4352 + q * 68 + ds + j * 4];
        o4[j] += p4;
      }
    float rinv = __builtin_amdgcn_rcpf(lsumv);
    unsigned int pk[8];
    #pragma unroll
    for (int j = 0; j < 4; ++j) {
      pk[2*j]   = cvtpk(o4[j][0] * rinv, o4[j][1] * rinv);
      pk[2*j+1] = cvtpk(o4[j][2] * rinv, o4[j][3] * rinv);
    }
    unsigned short* dst = &OT[((size_t)b * 2048 + nt * 64 + q) * 512 + h * 64 + ds];
    u32x4 s0 = {pk[0], pk[1], pk[2], pk[3]};
    u32x4 s1 = {pk[4], pk[5], pk[6], pk[7]};
    *(u32x4*)dst = s0;
    *(u32x4*)(dst + 8) = s1;
  }
}

__global__ __launch_bounds__(256) void k_out(
    const unsigned short* __restrict__ OT, const unsigned short* __restrict__ wmw,
    const float* __restrict__ bm, const float* __restrict__ fq,
    const float* __restrict__ g, const float* __restrict__ be,
    float* __restrict__ out)
{
  const int b = blockIdx.y;
  const int n0 = blockIdx.x * 16;
  const int t = threadIdx.x, w = t >> 6, l = t & 63, q = l >> 4, m16 = l & 15;

  __shared__ __attribute__((aligned(16))) unsigned short As[2][1024];
  __shared__ __attribute__((aligned(16))) unsigned short Bs[2][32768];
  __shared__ float ssum[4][16], ssq[4][16];

  f32x4 acc[8];
  const f32x4 fz = {0.f, 0.f, 0.f, 0.f};
  #pragma unroll
  for (int nf = 0; nf < 8; ++nf) acc[nf] = fz;

  const unsigned short* Abase = OT + ((size_t)b * 2048 + n0) * 512;
  const unsigned short* Bbase = wmw;

#define OUT_STAGE(BUF, KS)                                                          \
  {                                                                                 \
    if (t < 128) {                                                                  \
      int row = t >> 3, j = t & 7;                                                  \
      gl_lds16(Abase + (size_t)row * 512 + (KS) * 64 + ((j ^ (row & 7)) * 8),       \
               (char*)As[BUF] + w * 1024);                                          \
    }                                                                               \
    _Pragma("unroll")                                                               \
    for (int c = 0; c < 16; ++c) {                                                  \
      int slot = c * 256 + t;                                                       \
      int row = slot >> 3, j = slot & 7;                                            \
      gl_lds16(Bbase + (size_t)row * 512 + (KS) * 64 + ((j ^ (row & 7)) * 8),       \
               (char*)Bs[BUF] + (c * 256 + w * 64) * 16);                           \
    }                                                                               \
  }

  OUT_STAGE(0, 0)
  asm volatile("s_waitcnt vmcnt(0)" ::: "memory");
  __syncthreads();

  for (int ks = 0; ks < 8; ++ks) {
    const int cur = ks & 1;
    if (ks < 7) OUT_STAGE(cur ^ 1, ks + 1)
    #pragma unroll
    for (int kk = 0; kk < 2; ++kk) {
      bf16x8 av;
      {
        int row = m16;
        av = *(const bf16x8*)((const char*)As[cur] + row * 128 + (((kk * 4 + q) ^ (row & 7)) * 16));
      }
      #pragma unroll
      for (int nf = 0; nf < 8; ++nf) {
        int row = w * 128 + nf * 16 + m16;
        bf16x8 bv = *(const bf16x8*)((const char*)Bs[cur] + row * 128 + (((kk * 4 + q) ^ (row & 7)) * 16));
        acc[nf] = __builtin_amdgcn_mfma_f32_16x16x32_bf16(av, bv, acc[nf], 0, 0, 0);
      }
    }
    if (ks < 7) {
      asm volatile("s_waitcnt vmcnt(0)" ::: "memory");
      __syncthreads();
    }
  }
#undef OUT_STAGE

  float gv[8], bev[8], bmv[8];
  #pragma unroll
  for (int nf = 0; nf < 8; ++nf) {
    int c = w * 128 + nf * 16 + m16;
    gv[nf] = g[c]; bev[nf] = be[c]; bmv[nf] = bm[c];
  }
  #pragma unroll
  for (int nf = 0; nf < 8; ++nf) {
    int c = w * 128 + nf * 16 + m16;
    f32x4 res = *(const f32x4*)&fq[((size_t)b * 512 + c) * 2048 + n0 + q * 4];
    #pragma unroll
    for (int r = 0; r < 4; ++r)
      acc[nf][r] += bmv[nf] + res[r];
  }
  #pragma unroll
  for (int r = 0; r < 4; ++r) {
    float ps = 0.f, pss = 0.f;
    #pragma unroll
    for (int nf = 0; nf < 8; ++nf) {
      float v = acc[nf][r];
      ps += v; pss += v * v;
    }
    ps += __shfl_xor(ps, 1); pss += __shfl_xor(pss, 1);
    ps += __shfl_xor(ps, 2); pss += __shfl_xor(pss, 2);
    ps += __shfl_xor(ps, 4); pss += __shfl_xor(pss, 4);
    ps += __shfl_xor(ps, 8); pss += __shfl_xor(pss, 8);
    if (m16 == 0) {
      ssum[w][q * 4 + r] = ps;
      ssq[w][q * 4 + r] = pss;
    }
  }
  __syncthreads();
  #pragma unroll
  for (int r = 0; r < 4; ++r) {
    int nl = q * 4 + r;
    float S  = ssum[0][nl] + ssum[1][nl] + ssum[2][nl] + ssum[3][nl];
    float SS = ssq[0][nl] + ssq[1][nl] + ssq[2][nl] + ssq[3][nl];
    float mu = S * (1.f / 512.f);
    float var = SS * (1.f / 512.f) - mu * mu;
    float rstd = rsqrtf(var + 1e-5f);
    #pragma unroll
    for (int nf = 0; nf < 8; ++nf)
      acc[nf][r] = (acc[nf][r] - mu) * rstd * gv[nf] + bev[nf];
  }
  #pragma unroll
  for (int nf = 0; nf < 8; ++nf) {
    int c = w * 128 + nf * 16 + m16;
    *(f32x4*)&out[((size_t)b * 512 + c) * 2048 + n0 + q * 4] = acc[nf];
  }
}

// ---------------- launcher ----------------
extern "C" void kernel_launch(void* const* d_in, const int* in_sizes, int n_in,
                              void* d_out, int out_size, void* d_ws, size_t ws_size,
                              hipStream_t stream) {
  const float* fq  = (const float*)d_in[0];
  const float* fk  = (const float*)d_in[1];
  const int*   msk = (const int*)d_in[2];
  const float* Wq  = (const float*)d_in[3];
  const float* bq  = (const float*)d_in[4];
  const float* Wk  = (const float*)d_in[5];
  const float* bk  = (const float*)d_in[6];
  const float* Wf  = (const float*)d_in[7];
  const float* bfv = (const float*)d_in[8];
  const float* Wm  = (const float*)d_in[9];
  const float* bm  = (const float*)d_in[10];
  const float* lng = (const float*)d_in[11];
  const float* lnb = (const float*)d_in[12];
  float* out = (float*)d_out;

  char* ws = (char*)d_ws;
  const size_t MB = 1024 * 1024;
  unsigned short* xqt = (unsigned short*)(ws + 0 * MB);
  unsigned short* xkt = (unsigned short*)(ws + 4 * MB);
  unsigned short* wqb = (unsigned short*)(ws + 8 * MB);
  unsigned short* wkb = (unsigned short*)(ws + 8 * MB + 512 * 1024);
  unsigned short* wfb = (unsigned short*)(ws + 9 * MB);
  unsigned short* wmb = (unsigned short*)(ws + 9 * MB + 512 * 1024);
  unsigned short* Qb  = (unsigned short*)(ws + 10 * MB);
  unsigned short* Kb  = (unsigned short*)(ws + 14 * MB);
  unsigned short* VTb = (unsigned short*)(ws + 18 * MB);
  unsigned short* OTb = (unsigned short*)(ws + 22 * MB);
  unsigned int*   mbits = (unsigned int*)(ws + 26 * MB);

  // adaptive cooperative grid (host-side queries; graph-capture safe)
  int perCU = 0;
  hipError_t eo = hipOccupancyMaxActiveBlocksPerMultiprocessor(&perCU, k_fused, 256, 0);
  int nCU = 0, dev = 0;
  (void)hipGetDevice(&dev);
  hipError_t ea = hipDeviceGetAttribute(&nCU, hipDeviceAttributeMultiprocessorCount, dev);
  int maxb = (eo == hipSuccess && ea == hipSuccess && perCU > 0 && nCU > 0) ? perCU * nCU : 0;
  int nb = (maxb >= 512) ? 512 : (maxb >= 256 ? 256 : 0);

  hipError_t le = hipErrorUnknown;
  if (nb > 0) {
    void* args[] = {
      (void*)&fq, (void*)&fk, (void*)&msk, (void*)&Wq, (void*)&bq, (void*)&Wk, (void*)&bk,
      (void*)&Wf, (void*)&bfv, (void*)&Wm, (void*)&bm, (void*)&lng, (void*)&lnb, (void*)&out,
      (void*)&xqt, (void*)&xkt, (void*)&wqb, (void*)&wkb, (void*)&wfb, (void*)&wmb,
      (void*)&Qb, (void*)&Kb, (void*)&VTb, (void*)&OTb, (void*)&mbits
    };
    le = hipLaunchCooperativeKernel((void*)k_fused, dim3(nb), dim3(256), args, 0, stream);
  }
  if (le != hipSuccess) {
    // fallback: proven 4-kernel pipeline
    hipLaunchKernelGGL(k_pre, dim3(3073), dim3(256), 0, stream,
                       fq, fk, Wq, Wk, Wf, Wm, msk, xqt, xkt, wqb, wkb, wfb, wmb, mbits);
    hipLaunchKernelGGL(k_proj, dim3(768), dim3(256), 0, stream,
                       xqt, xkt, wqb, wkb, wfb, bq, bk, bfv, Qb, Kb, VTb);
    hipLaunchKernelGGL(k_attn2, dim3(512), dim3(256), 0, stream, Qb, Kb, VTb, mbits, OTb);
    hipLaunchKernelGGL(k_out, dim3(128, 2), dim3(256), 0, stream,
                       OTb, wmb, bm, fq, lng, lnb, out);
  }
}

// Round 15
// 68.563 us; speedup vs baseline: 4.2643x; 4.2643x over previous
//
#include <hip/hip_runtime.h>
#include <hip/hip_bf16.h>

// B=2, D=512, N=2048, H=8, head=64.

using bf16x8 = __attribute__((ext_vector_type(8))) __bf16;
using f32x4  = __attribute__((ext_vector_type(4))) float;
using f32x16 = __attribute__((ext_vector_type(16))) float;
using us8    = __attribute__((ext_vector_type(8))) unsigned short;
using u32x4  = __attribute__((ext_vector_type(4))) unsigned int;

__device__ __forceinline__ unsigned short f2b(float f) {
  unsigned int u = __builtin_bit_cast(unsigned int, f);
  u += 0x7fffu + ((u >> 16) & 1u);
  return (unsigned short)(u >> 16);
}
__device__ __forceinline__ float b2f(unsigned short s) {
  unsigned int u = ((unsigned int)s) << 16;
  return __builtin_bit_cast(float, u);
}
__device__ __forceinline__ unsigned int cvtpk(float lo, float hi) {
  unsigned int w;
  asm("v_cvt_pk_bf16_f32 %0, %1, %2" : "=v"(w) : "v"(lo), "v"(hi));
  return w;
}
__device__ __forceinline__ void gl_lds16(const void* g, void* l) {
  __builtin_amdgcn_global_load_lds((const __attribute__((address_space(1))) void*)g,
                                   (__attribute__((address_space(3))) void*)l, 16, 0, 0);
}

// ------- fused pre-pass: feats transpose (f32->bf16) + weight permute + mask bias -------
__global__ __launch_bounds__(256) void k_pre(
    const float* __restrict__ fq, const float* __restrict__ fk,
    const float* __restrict__ Wq, const float* __restrict__ Wk,
    const float* __restrict__ Wf, const float* __restrict__ Wm,
    const int* __restrict__ mask,
    unsigned short* __restrict__ xqt, unsigned short* __restrict__ xkt,
    unsigned short* __restrict__ wqb, unsigned short* __restrict__ wkb,
    unsigned short* __restrict__ wfb, unsigned short* __restrict__ wmb,
    float* __restrict__ biasf)
{
  const int id = blockIdx.x;
  const int t = threadIdx.x;
  __shared__ float tile[64][65];

  if (id < 1024) {
    const int which = id >> 9;
    const int b = (id >> 8) & 1;
    const int i0 = ((id >> 5) & 7) * 64;
    const int n0 = (id & 31) * 64;
    const float* __restrict__ src = which ? fk : fq;
    unsigned short* __restrict__ dst = which ? xkt : xqt;
    const int cl = t & 63, rw = t >> 6;
    #pragma unroll
    for (int rr = 0; rr < 16; ++rr) {
      int il = rr * 4 + rw;
      tile[il][cl] = src[((size_t)b * 512 + i0 + il) * 2048 + n0 + cl];
    }
    __syncthreads();
    const int ci = (t & 31) * 2, rhalf = t >> 5;
    #pragma unroll
    for (int rr = 0; rr < 8; ++rr) {
      int nl = rr * 8 + rhalf;
      unsigned int v = (unsigned int)f2b(tile[ci][nl]) |
                       ((unsigned int)f2b(tile[ci + 1][nl]) << 16);
      *(unsigned int*)&dst[((size_t)b * 2048 + n0 + nl) * 512 + i0 + ci] = v;
    }
  } else if (id < 3072) {
    const int r = id - 1024;
    const int mat = r >> 9, cp = r & 511;
    if (mat < 3) {
      const float* W = (mat == 0) ? Wq : (mat == 1) ? Wk : Wf;
      unsigned short* O = (mat == 0) ? wqb : (mat == 1) ? wkb : wfb;
      const int orig = (cp & 63) * 8 + (cp >> 6);   // d*8+h
      for (int j = t; j < 512; j += 256)
        O[cp * 512 + j] = f2b(W[orig * 512 + j]);
    } else {
      for (int j = t; j < 512; j += 256) {
        int h = j >> 6, d = j & 63;
        wmb[cp * 512 + j] = f2b(Wm[cp * 512 + d * 8 + h]);
      }
    }
  } else {
    const int r = id - 3072;
    if (r < 16) {
      int i = r * 256 + t;
      biasf[i] = mask[i] ? 0.f : -100000.f;
    }
  }
}

// -------- QKV projections: 128x64 NT tiles, 768 blocks (3/CU exact), gl_lds 2-phase --------
__global__ __launch_bounds__(256) void k_proj(
    const unsigned short* __restrict__ xqt, const unsigned short* __restrict__ xkt,
    const unsigned short* __restrict__ wqp, const unsigned short* __restrict__ wkp,
    const unsigned short* __restrict__ wfp,
    const float* __restrict__ bq, const float* __restrict__ bk, const float* __restrict__ bfv,
    unsigned short* __restrict__ Qb, unsigned short* __restrict__ Kb, unsigned short* __restrict__ VTb)
{
  const int lid = blockIdx.x;                     // 0..767
  const int orig = (lid & 7) * 96 + (lid >> 3);   // bijective (768 = 8*96)
  const int z = orig / 128;                       // 0..5
  const int bid = orig % 128;
  const int b = z / 3, proj = z % 3;
  const int t = threadIdx.x, w = t >> 6, l = t & 63, q = l >> 4, m16 = l & 15;
  const int wm = w >> 1, wn = w & 1;              // 2x2 waves; wave tile 64x32

  __shared__ __attribute__((aligned(16))) unsigned short As[2][8192];   // 128x64
  __shared__ __attribute__((aligned(16))) unsigned short Bs[2][4096];   // 64x64

  const unsigned short* A;
  const unsigned short* Bt;
  int mt, nt_;
  if (proj < 2) {
    mt = bid >> 3; nt_ = bid & 7;                 // 16 x 8
    A  = (proj == 0 ? xqt : xkt) + (size_t)b * 2048 * 512 + (size_t)mt * 128 * 512;
    Bt = (proj == 0 ? wqp : wkp) + (size_t)nt_ * 64 * 512;
  } else {
    mt = bid & 3; nt_ = bid >> 2;                 // 4 x 32
    A  = wfp + (size_t)mt * 128 * 512;
    Bt = xkt + (size_t)b * 2048 * 512 + (size_t)nt_ * 64 * 512;
  }

  f32x4 acc[4][2];
  const f32x4 fz = {0.f, 0.f, 0.f, 0.f};
  #pragma unroll
  for (int mf = 0; mf < 4; ++mf)
    #pragma unroll
    for (int nf = 0; nf < 2; ++nf) acc[mf][nf] = fz;

#define PROJ_STAGE(BUF, KS)                                                          \
  {                                                                                  \
    _Pragma("unroll")                                                                \
    for (int c = 0; c < 4; ++c) {                                                    \
      int slot = c * 256 + t;                                                        \
      int row = slot >> 3, j = slot & 7;                                             \
      gl_lds16(A + (size_t)row * 512 + (KS) * 64 + ((j ^ (row & 7)) * 8),            \
               (char*)As[BUF] + (c * 256 + w * 64) * 16);                            \
    }                                                                                \
    _Pragma("unroll")                                                                \
    for (int c = 0; c < 2; ++c) {                                                    \
      int slot = c * 256 + t;                                                        \
      int row = slot >> 3, j = slot & 7;                                             \
      gl_lds16(Bt + (size_t)row * 512 + (KS) * 64 + ((j ^ (row & 7)) * 8),           \
               (char*)Bs[BUF] + (c * 256 + w * 64) * 16);                            \
    }                                                                                \
  }

  PROJ_STAGE(0, 0)
  asm volatile("s_waitcnt vmcnt(0)" ::: "memory");
  __syncthreads();

  for (int ks = 0; ks < 8; ++ks) {
    const int cur = ks & 1;
    if (ks < 7) PROJ_STAGE(cur ^ 1, ks + 1)
    #pragma unroll
    for (int kk = 0; kk < 2; ++kk) {
      bf16x8 av[4], bv[2];
      #pragma unroll
      for (int mf = 0; mf < 4; ++mf) {
        int row = wm * 64 + mf * 16 + m16;
        av[mf] = *(const bf16x8*)&As[cur][row * 64 + (((kk * 4 + q) ^ (row & 7)) << 3)];
      }
      #pragma unroll
      for (int nf = 0; nf < 2; ++nf) {
        int row = wn * 32 + nf * 16 + m16;
        bv[nf] = *(const bf16x8*)&Bs[cur][row * 64 + (((kk * 4 + q) ^ (row & 7)) << 3)];
      }
      #pragma unroll
      for (int mf = 0; mf < 4; ++mf)
        #pragma unroll
        for (int nf = 0; nf < 2; ++nf)
          acc[mf][nf] = __builtin_amdgcn_mfma_f32_16x16x32_bf16(av[mf], bv[nf], acc[mf][nf], 0, 0, 0);
    }
    if (ks < 7) {
      asm volatile("s_waitcnt vmcnt(0)" ::: "memory");
      __syncthreads();
    }
  }
#undef PROJ_STAGE

  const float QSCALE = 0.18033688011112042f;   // log2(e)/8 folded into Q

  if (proj < 2) {
    const float* bias = (proj == 0) ? bq : bk;
    unsigned short* dst = (proj == 0) ? Qb : Kb;
    #pragma unroll
    for (int mf = 0; mf < 4; ++mf)
      #pragma unroll
      for (int nf = 0; nf < 2; ++nf)
        #pragma unroll
        for (int r = 0; r < 4; ++r) {
          int n  = mt * 128 + wm * 64 + mf * 16 + q * 4 + r;
          int cp = nt_ * 64 + wn * 32 + nf * 16 + m16;
          int h = cp >> 6, d = cp & 63;
          float v = acc[mf][nf][r] + bias[d * 8 + h];
          if (proj == 0) v *= QSCALE;
          dst[((size_t)(b * 8 + h) * 2048 + n) * 64 + d] = f2b(v);
        }
  } else {
    #pragma unroll
    for (int mf = 0; mf < 4; ++mf)
      #pragma unroll
      for (int nf = 0; nf < 2; ++nf)
        #pragma unroll
        for (int r = 0; r < 4; ++r) {
          int cp = mt * 128 + wm * 64 + mf * 16 + q * 4 + r;
          int n  = nt_ * 64 + wn * 32 + nf * 16 + m16;
          int h = cp >> 6, d = cp & 63;
          float v = acc[mf][nf][r] + bfv[d * 8 + h];
          VTb[((size_t)(b * 8 + h) * 64 + d) * 2048 + n] = f2b(v);
        }
  }
}

// ---------------- flash attention (R5-verified): wave-split KV + LDS cross-wave combine ----------------
__global__ __launch_bounds__(256, 2) void k_attn2(
    const unsigned short* __restrict__ Qb, const unsigned short* __restrict__ Kb,
    const unsigned short* __restrict__ VTb, const float* __restrict__ biasf,
    unsigned short* __restrict__ OT)
{
  const int lid = blockIdx.x;                       // 0..511
  const int orig = ((lid & 7) << 6) | (lid >> 3);   // bijective (512 = 8*64)
  const int bh = orig >> 5, b = bh >> 3, h = bh & 7;
  const int nt = orig & 31;
  const int t = threadIdx.x, w = t >> 6, l = t & 63;
  const int q31 = l & 31, hi = l >> 5;

  __shared__ __attribute__((aligned(16))) char lds_all[70656];
  char* kbuf = lds_all + w * 8192;            // 2 x 4KB K double-buffer (per wave)
  char* vbuf = lds_all + 32768 + w * 8192;    // 2 x 4KB V double-buffer (per wave)

  const unsigned short* Kp = Kb + (size_t)bh * (2048 * 64);
  const unsigned short* Vp = VTb + (size_t)bh * (64 * 2048);
  const float* brow = biasf + b * 2048;

  bf16x8 qfr[2][4];
  {
    const unsigned short* Qp = Qb + ((size_t)bh * 2048 + nt * 64) * 64;
    #pragma unroll
    for (int qf = 0; qf < 2; ++qf)
      #pragma unroll
      for (int tq = 0; tq < 4; ++tq)
        qfr[qf][tq] = *(const bf16x8*)&Qp[(qf * 32 + q31) * 64 + tq * 16 + hi * 8];
  }

  f32x16 z16;
  #pragma unroll
  for (int r = 0; r < 16; ++r) z16[r] = 0.f;

  f32x16 oacc[2][2];   // [df][qf]
  #pragma unroll
  for (int i = 0; i < 2; ++i)
    #pragma unroll
    for (int j2 = 0; j2 < 2; ++j2) oacc[i][j2] = z16;
  float lpart[2] = {0.f, 0.f};

  const int kr3 = l >> 3, ks3 = l & 7;
  const int vr4 = l >> 2, vs2 = l & 3;

  {
    int kv0 = w * 32;
    #pragma unroll
    for (int j = 0; j < 4; ++j)
      gl_lds16(Kp + (size_t)(kv0 + j * 8 + kr3) * 64 + (ks3 ^ kr3) * 8, kbuf + j * 1024);
    #pragma unroll
    for (int j = 0; j < 4; ++j) {
      int d = j * 16 + vr4;
      gl_lds16(Vp + (size_t)d * 2048 + kv0 + (vs2 ^ (d & 3)) * 8, vbuf + j * 1024);
    }
  }

  #pragma unroll 2
  for (int i = 0; i < 16; ++i) {
    const int bufi = i & 1;
    const int kv0 = (w + 4 * i) * 32;

    float4 bias[4];
    #pragma unroll
    for (int g = 0; g < 4; ++g)
      bias[g] = *(const float4*)&brow[kv0 + g * 8 + hi * 4];

    if (i < 15) {
      const int kvn = (w + 4 * (i + 1)) * 32;
      char* kb2 = kbuf + (bufi ^ 1) * 4096;
      char* vb2 = vbuf + (bufi ^ 1) * 4096;
      #pragma unroll
      for (int j = 0; j < 4; ++j)
        gl_lds16(Kp + (size_t)(kvn + j * 8 + kr3) * 64 + (ks3 ^ kr3) * 8, kb2 + j * 1024);
      #pragma unroll
      for (int j = 0; j < 4; ++j) {
        int d = j * 16 + vr4;
        gl_lds16(Vp + (size_t)d * 2048 + kvn + (vs2 ^ (d & 3)) * 8, vb2 + j * 1024);
      }
      asm volatile("s_waitcnt vmcnt(8)" ::: "memory");
    } else {
      asm volatile("s_waitcnt vmcnt(0)" ::: "memory");
    }
    __builtin_amdgcn_sched_barrier(0);

    const char* kb = kbuf + bufi * 4096;
    const char* vb = vbuf + bufi * 4096;

    bf16x8 ak[4];
    #pragma unroll
    for (int tq = 0; tq < 4; ++tq)
      ak[tq] = *(const bf16x8*)(kb + q31 * 128 + ((((tq << 1) | hi) ^ (q31 & 7)) * 16));

    f32x16 sacc[2];
    __builtin_amdgcn_s_setprio(1);
    sacc[0] = __builtin_amdgcn_mfma_f32_32x32x16_bf16(ak[0], qfr[0][0], z16, 0, 0, 0);
    sacc[1] = __builtin_amdgcn_mfma_f32_32x32x16_bf16(ak[0], qfr[1][0], z16, 0, 0, 0);
    #pragma unroll
    for (int tq = 1; tq < 4; ++tq) {
      sacc[0] = __builtin_amdgcn_mfma_f32_32x32x16_bf16(ak[tq], qfr[0][tq], sacc[0], 0, 0, 0);
      sacc[1] = __builtin_amdgcn_mfma_f32_32x32x16_bf16(ak[tq], qfr[1][tq], sacc[1], 0, 0, 0);
    }
    __builtin_amdgcn_s_setprio(0);

    bf16x8 av[2][2];
    #pragma unroll
    for (int df = 0; df < 2; ++df)
      #pragma unroll
      for (int tt = 0; tt < 2; ++tt)
        av[df][tt] = *(const bf16x8*)(vb + (df * 32 + q31) * 64 + ((((tt << 1) | hi) ^ (q31 & 3)) * 16));

    #pragma unroll
    for (int qf = 0; qf < 2; ++qf) {
      float e[16];
      #pragma unroll
      for (int g = 0; g < 4; ++g) {
        e[g*4+0] = __builtin_amdgcn_exp2f(sacc[qf][g*4+0] + bias[g].x);
        e[g*4+1] = __builtin_amdgcn_exp2f(sacc[qf][g*4+1] + bias[g].y);
        e[g*4+2] = __builtin_amdgcn_exp2f(sacc[qf][g*4+2] + bias[g].z);
        e[g*4+3] = __builtin_amdgcn_exp2f(sacc[qf][g*4+3] + bias[g].w);
      }
      float s0 = 0.f;
      #pragma unroll
      for (int r = 0; r < 16; ++r) s0 += e[r];
      lpart[qf] += s0;

      unsigned int W[8];
      #pragma unroll
      for (int j = 0; j < 8; ++j) W[j] = cvtpk(e[2*j], e[2*j+1]);
      asm("v_permlane32_swap_b32 %0, %1" : "+v"(W[0]), "+v"(W[2]));
      asm("v_permlane32_swap_b32 %0, %1" : "+v"(W[1]), "+v"(W[3]));
      asm("v_permlane32_swap_b32 %0, %1" : "+v"(W[4]), "+v"(W[6]));
      asm("v_permlane32_swap_b32 %0, %1" : "+v"(W[5]), "+v"(W[7]));
      u32x4 lo4 = {W[0], W[1], W[2], W[3]};
      u32x4 hi4 = {W[4], W[5], W[6], W[7]};
      bf16x8 pb0 = __builtin_bit_cast(bf16x8, lo4);
      bf16x8 pb1 = __builtin_bit_cast(bf16x8, hi4);

      __builtin_amdgcn_s_setprio(1);
      oacc[0][qf] = __builtin_amdgcn_mfma_f32_32x32x16_bf16(av[0][0], pb0, oacc[0][qf], 0, 0, 0);
      oacc[0][qf] = __builtin_amdgcn_mfma_f32_32x32x16_bf16(av[0][1], pb1, oacc[0][qf], 0, 0, 0);
      oacc[1][qf] = __builtin_amdgcn_mfma_f32_32x32x16_bf16(av[1][0], pb0, oacc[1][qf], 0, 0, 0);
      oacc[1][qf] = __builtin_amdgcn_mfma_f32_32x32x16_bf16(av[1][1], pb1, oacc[1][qf], 0, 0, 0);
      __builtin_amdgcn_s_setprio(0);
    }
  }

  // ---- cross-wave combine: O = sum_w O_w, l = sum_w l_w ----
  float* pc = (float*)lds_all;                 // [w][q 64][68 floats]
  float* ls = (float*)(lds_all + 69632);       // [w][q 64]
  __syncthreads();
  #pragma unroll
  for (int qf = 0; qf < 2; ++qf) {
    float lfull = lpart[qf] + __shfl_xor(lpart[qf], 32);
    int qq = qf * 32 + q31;
    if (hi == 0) ls[w * 64 + qq] = lfull;
    #pragma unroll
    for (int df = 0; df < 2; ++df)
      #pragma unroll
      for (int g = 0; g < 4; ++g) {
        f32x4 v4 = {oacc[df][qf][g*4+0], oacc[df][qf][g*4+1],
                    oacc[df][qf][g*4+2], oacc[df][qf][g*4+3]};
        *(f32x4*)&pc[w * 4352 + qq * 68 + df * 32 + g * 8 + hi * 4] = v4;
      }
  }
  __syncthreads();
  {
    const int q = t >> 2, ds = (t & 3) * 16;
    float lsumv = ls[q] + ls[64 + q] + ls[128 + q] + ls[192 + q];
    f32x4 o4[4];
    #pragma unroll
    for (int j = 0; j < 4; ++j) o4[j] = *(const f32x4*)&pc[q * 68 + ds + j * 4];
    #pragma unroll
    for (int ww = 1; ww < 4; ++ww)
      #pragma unroll
      for (int j = 0; j < 4; ++j) {
        f32x4 p4 = *(const f32x4*)&pc[ww * 4352 + q * 68 + ds + j * 4];
        o4[j] += p4;
      }
    float rinv = __builtin_amdgcn_rcpf(lsumv);
    unsigned int pk[8];
    #pragma unroll
    for (int j = 0; j < 4; ++j) {
      pk[2*j]   = cvtpk(o4[j][0] * rinv, o4[j][1] * rinv);
      pk[2*j+1] = cvtpk(o4[j][2] * rinv, o4[j][3] * rinv);
    }
    unsigned short* dst = &OT[((size_t)b * 2048 + nt * 64 + q) * 512 + h * 64 + ds];
    u32x4 s0 = {pk[0], pk[1], pk[2], pk[3]};
    u32x4 s1 = {pk[4], pk[5], pk[6], pk[7]};
    *(u32x4*)dst = s0;
    *(u32x4*)(dst + 8) = s1;
  }
}

// --------- fused: final projection + residual + channel-LN; 16-row tiles -> 256 blocks ---------
__global__ __launch_bounds__(256) void k_out(
    const unsigned short* __restrict__ OT, const unsigned short* __restrict__ wmw,
    const float* __restrict__ bm, const float* __restrict__ fq,
    const float* __restrict__ g, const float* __restrict__ be,
    float* __restrict__ out)
{
  const int b = blockIdx.y;
  const int n0 = blockIdx.x * 16;
  const int t = threadIdx.x, w = t >> 6, l = t & 63, q = l >> 4, m16 = l & 15;

  __shared__ __attribute__((aligned(16))) unsigned short As[2][1024];    // 2 x 2 KB (16x64)
  __shared__ __attribute__((aligned(16))) unsigned short Bs[2][32768];   // 2 x 64 KB (512x64)
  __shared__ float ssum[4][16], ssq[4][16];

  f32x4 acc[8];
  const f32x4 fz = {0.f, 0.f, 0.f, 0.f};
  #pragma unroll
  for (int nf = 0; nf < 8; ++nf) acc[nf] = fz;

  const unsigned short* Abase = OT + ((size_t)b * 2048 + n0) * 512;
  const unsigned short* Bbase = wmw;

#define OUT_STAGE(BUF, KS)                                                          \
  {                                                                                 \
    if (t < 128) {                                                                  \
      int row = t >> 3, j = t & 7;                                                  \
      gl_lds16(Abase + (size_t)row * 512 + (KS) * 64 + ((j ^ (row & 7)) * 8),       \
               (char*)As[BUF] + w * 1024);                                          \
    }                                                                               \
    _Pragma("unroll")                                                               \
    for (int c = 0; c < 16; ++c) {                                                  \
      int slot = c * 256 + t;                                                       \
      int row = slot >> 3, j = slot & 7;                                            \
      gl_lds16(Bbase + (size_t)row * 512 + (KS) * 64 + ((j ^ (row & 7)) * 8),       \
               (char*)Bs[BUF] + (c * 256 + w * 64) * 16);                           \
    }                                                                               \
  }

  OUT_STAGE(0, 0)
  asm volatile("s_waitcnt vmcnt(0)" ::: "memory");
  __syncthreads();

  for (int ks = 0; ks < 8; ++ks) {
    const int cur = ks & 1;
    if (ks < 7) OUT_STAGE(cur ^ 1, ks + 1)
    #pragma unroll
    for (int kk = 0; kk < 2; ++kk) {
      bf16x8 av;
      {
        int row = m16;
        av = *(const bf16x8*)((const char*)As[cur] + row * 128 + (((kk * 4 + q) ^ (row & 7)) * 16));
      }
      #pragma unroll
      for (int nf = 0; nf < 8; ++nf) {
        int row = w * 128 + nf * 16 + m16;
        bf16x8 bv = *(const bf16x8*)((const char*)Bs[cur] + row * 128 + (((kk * 4 + q) ^ (row & 7)) * 16));
        acc[nf] = __builtin_amdgcn_mfma_f32_16x16x32_bf16(av, bv, acc[nf], 0, 0, 0);
      }
    }
    if (ks < 7) {
      asm volatile("s_waitcnt vmcnt(0)" ::: "memory");
      __syncthreads();
    }
  }
#undef OUT_STAGE

  float gv[8], bev[8], bmv[8];
  #pragma unroll
  for (int nf = 0; nf < 8; ++nf) {
    int c = w * 128 + nf * 16 + m16;
    gv[nf] = g[c]; bev[nf] = be[c]; bmv[nf] = bm[c];
  }
  #pragma unroll
  for (int nf = 0; nf < 8; ++nf) {
    int c = w * 128 + nf * 16 + m16;
    f32x4 res = *(const f32x4*)&fq[((size_t)b * 512 + c) * 2048 + n0 + q * 4];
    #pragma unroll
    for (int r = 0; r < 4; ++r)
      acc[nf][r] += bmv[nf] + res[r];
  }
  #pragma unroll
  for (int r = 0; r < 4; ++r) {
    float ps = 0.f, pss = 0.f;
    #pragma unroll
    for (int nf = 0; nf < 8; ++nf) {
      float v = acc[nf][r];
      ps += v; pss += v * v;
    }
    ps += __shfl_xor(ps, 1); pss += __shfl_xor(pss, 1);
    ps += __shfl_xor(ps, 2); pss += __shfl_xor(pss, 2);
    ps += __shfl_xor(ps, 4); pss += __shfl_xor(pss, 4);
    ps += __shfl_xor(ps, 8); pss += __shfl_xor(pss, 8);
    if (m16 == 0) {
      ssum[w][q * 4 + r] = ps;
      ssq[w][q * 4 + r] = pss;
    }
  }
  __syncthreads();
  #pragma unroll
  for (int r = 0; r < 4; ++r) {
    int nl = q * 4 + r;
    float S  = ssum[0][nl] + ssum[1][nl] + ssum[2][nl] + ssum[3][nl];
    float SS = ssq[0][nl] + ssq[1][nl] + ssq[2][nl] + ssq[3][nl];
    float mu = S * (1.f / 512.f);
    float var = SS * (1.f / 512.f) - mu * mu;
    float rstd = rsqrtf(var + 1e-5f);
    #pragma unroll
    for (int nf = 0; nf < 8; ++nf)
      acc[nf][r] = (acc[nf][r] - mu) * rstd * gv[nf] + bev[nf];
  }
  #pragma unroll
  for (int nf = 0; nf < 8; ++nf) {
    int c = w * 128 + nf * 16 + m16;
    *(f32x4*)&out[((size_t)b * 512 + c) * 2048 + n0 + q * 4] = acc[nf];
  }
}

// ---------------- launcher ----------------
extern "C" void kernel_launch(void* const* d_in, const int* in_sizes, int n_in,
                              void* d_out, int out_size, void* d_ws, size_t ws_size,
                              hipStream_t stream) {
  const float* fq  = (const float*)d_in[0];
  const float* fk  = (const float*)d_in[1];
  const int*   msk = (const int*)d_in[2];
  const float* Wq  = (const float*)d_in[3];
  const float* bq  = (const float*)d_in[4];
  const float* Wk  = (const float*)d_in[5];
  const float* bk  = (const float*)d_in[6];
  const float* Wf  = (const float*)d_in[7];
  const float* bfv = (const float*)d_in[8];
  const float* Wm  = (const float*)d_in[9];
  const float* bm  = (const float*)d_in[10];
  const float* lng = (const float*)d_in[11];
  const float* lnb = (const float*)d_in[12];
  float* out = (float*)d_out;

  char* ws = (char*)d_ws;
  const size_t MB = 1024 * 1024;
  unsigned short* xqt = (unsigned short*)(ws + 0 * MB);        // 4 MB  [b][n][512] bf16
  unsigned short* xkt = (unsigned short*)(ws + 4 * MB);        // 4 MB
  unsigned short* wqb = (unsigned short*)(ws + 8 * MB);        // 512 KB
  unsigned short* wkb = (unsigned short*)(ws + 8 * MB + 512 * 1024);
  unsigned short* wfb = (unsigned short*)(ws + 9 * MB);
  unsigned short* wmb = (unsigned short*)(ws + 9 * MB + 512 * 1024);
  unsigned short* Qb  = (unsigned short*)(ws + 10 * MB);       // 4 MB  [bh][n][64]
  unsigned short* Kb  = (unsigned short*)(ws + 14 * MB);       // 4 MB  [bh][m][64]
  unsigned short* VTb = (unsigned short*)(ws + 18 * MB);       // 4 MB  [bh][64][m]
  unsigned short* OTb = (unsigned short*)(ws + 22 * MB);       // 4 MB  [b][n][512]
  float*          biasf = (float*)(ws + 26 * MB);              // 16 KB

  hipLaunchKernelGGL(k_pre, dim3(3088), dim3(256), 0, stream,
                     fq, fk, Wq, Wk, Wf, Wm, msk, xqt, xkt, wqb, wkb, wfb, wmb, biasf);
  hipLaunchKernelGGL(k_proj, dim3(768), dim3(256), 0, stream,
                     xqt, xkt, wqb, wkb, wfb, bq, bk, bfv, Qb, Kb, VTb);
  hipLaunchKernelGGL(k_attn2, dim3(512), dim3(256), 0, stream, Qb, Kb, VTb, biasf, OTb);
  hipLaunchKernelGGL(k_out, dim3(128, 2), dim3(256), 0, stream,
                     OTb, wmb, bm, fq, lng, lnb, out);
}